// Round 25
// baseline (394.818 us; speedup 1.0000x reference)
//
#include <hip/hip_runtime.h>
#include <hip/hip_bf16.h>

typedef __hip_bfloat16 bf16;
typedef __attribute__((ext_vector_type(8))) short short8;
typedef __attribute__((ext_vector_type(4))) float f32x4;

#define S_LEN 4096
#define HID_DIM 2048

// 1/sqrt(128) * log2(e): folded into Q so softmax runs in exp2 domain
#define QSCALE ((float)(0.08838834764831845 * 1.4426950408889634))

__device__ __forceinline__ void gld_lds16(const void* g, void* l) {
  __builtin_amdgcn_global_load_lds(
      (const __attribute__((address_space(1))) void*)g,
      (__attribute__((address_space(3))) void*)l, 16, 0, 0);
}

__device__ __forceinline__ float fexp2(float x) {
  return __builtin_amdgcn_exp2f(x);  // bare v_exp_f32
}

__device__ __forceinline__ unsigned cvtpk_bf16(float lo, float hi) {
  unsigned r;
  asm("v_cvt_pk_bf16_f32 %0, %1, %2" : "=v"(r) : "v"(lo), "v"(hi));
  return r;
}

// ---------------- fused fp32 -> bf16 convert (hs, wq, wk, wv) ----------------
__global__ __launch_bounds__(256) void k_cvt4(
    const float* __restrict__ hs, const float* __restrict__ wq,
    const float* __restrict__ wk, const float* __restrict__ wv,
    bf16* __restrict__ Ah, bf16* __restrict__ Wqkv) {
  long u = (long)blockIdx.x * 256 + threadIdx.x;  // 8-elem unit index
  const float* src;
  bf16* dst;
  if (u < 1048576) {
    src = hs; dst = Ah;
  } else if (u < 1572864) {
    u -= 1048576; src = wq; dst = Wqkv;
  } else if (u < 1835008) {
    u -= 1572864; src = wk; dst = Wqkv + (long)2048 * 2048;
  } else {
    u -= 1835008; src = wv; dst = Wqkv + (long)3072 * 2048;
  }
  const long i = u * 8;
  float4 a = *reinterpret_cast<const float4*>(src + i);
  float4 b = *reinterpret_cast<const float4*>(src + i + 4);
  float v[8] = {a.x, a.y, a.z, a.w, b.x, b.y, b.z, b.w};
  short8 o;
#pragma unroll
  for (int j = 0; j < 8; ++j) {
    bf16 h = __float2bfloat16(v[j]);
    o[j] = *reinterpret_cast<short*>(&h);
  }
  *reinterpret_cast<short8*>(dst + i) = o;
}

// bijective XCD swizzle for nwg % 8 == 0 (T1, m204)
__device__ __forceinline__ int2 xcd_swz(int nx) {
  const int bid = blockIdx.y * nx + blockIdx.x;
  const int nwg = nx * gridDim.y;
  const int q = nwg >> 3;
  const int swz = (bid & 7) * q + (bid >> 3);
  return make_int2(swz % nx, swz / nx);
}

// ------- 256^2-tile bf16 GEMM, C = A * B^T, counted-vmcnt pipeline ---------
template <typename OutT>
__global__ __launch_bounds__(512, 1) void k_gemm256(
    const bf16* __restrict__ A, const bf16* __restrict__ B,
    OutT* __restrict__ C, int M, int N, int K) {
  __shared__ bf16 Al[2][256 * 64];   // 64 KB
  __shared__ bf16 Bl[2][256 * 64];   // 64 KB
  const int tid = threadIdx.x;
  const int lane = tid & 63;
  const int wid = tid >> 6;
  const int wr = wid >> 2;
  const int wc = wid & 3;
  const int2 bxy = xcd_swz(gridDim.x);
  const long brow = (long)bxy.y * 256;
  const long bcol = (long)bxy.x * 256;
  const int NT = K >> 6;

  auto stage = [&](int kt, int buf) {
    const bf16* At = A + brow * K + kt * 64;
    const bf16* Bt = B + bcol * K + kt * 64;
#pragma unroll
    for (int i = 0; i < 4; ++i) {
      const int ch = tid + i * 512;
      const int row = ch >> 3;
      const int j = (ch & 7) ^ (row & 7);
      gld_lds16(At + (size_t)row * K + j * 8, &Al[buf][(wid * 64 + i * 512) * 8]);
    }
#pragma unroll
    for (int i = 0; i < 4; ++i) {
      const int ch = tid + i * 512;
      const int row = ch >> 3;
      const int j = (ch & 7) ^ (row & 7);
      gld_lds16(Bt + (size_t)row * K + j * 8, &Bl[buf][(wid * 64 + i * 512) * 8]);
    }
  };

  f32x4 acc0[4][4], acc1[4][4];
#pragma unroll
  for (int m = 0; m < 4; ++m)
#pragma unroll
    for (int n = 0; n < 4; ++n) {
      acc0[m][n] = (f32x4){0.f, 0.f, 0.f, 0.f};
      acc1[m][n] = (f32x4){0.f, 0.f, 0.f, 0.f};
    }

  const int l15 = lane & 15;
  const int cp0 = ((lane >> 4) ^ (lane & 7)) * 8;
  const int cp1 = ((4 + (lane >> 4)) ^ (lane & 7)) * 8;

  stage(0, 0);
  stage(1, 1);
  asm volatile("s_waitcnt vmcnt(8)" ::: "memory");
  __builtin_amdgcn_s_barrier();

  for (int kt = 0; kt < NT; ++kt) {
    const bf16* Ab = &Al[kt & 1][0];
    const bf16* Bb = &Bl[kt & 1][0];
    short8 bB[4][2], aA[4][2];
#pragma unroll
    for (int n = 0; n < 4; ++n) {
      const int rb = (wc * 64 + n * 16 + l15) * 64;
      bB[n][0] = *reinterpret_cast<const short8*>(&Bb[rb + cp0]);
      bB[n][1] = *reinterpret_cast<const short8*>(&Bb[rb + cp1]);
    }
#pragma unroll
    for (int m = 0; m < 4; ++m) {
      const int ra = (wr * 128 + m * 16 + l15) * 64;
      aA[m][0] = *reinterpret_cast<const short8*>(&Ab[ra + cp0]);
      aA[m][1] = *reinterpret_cast<const short8*>(&Ab[ra + cp1]);
    }
    __builtin_amdgcn_s_setprio(1);
#pragma unroll
    for (int m = 0; m < 4; ++m)
#pragma unroll
      for (int n = 0; n < 4; ++n) {
        acc0[m][n] = __builtin_amdgcn_mfma_f32_16x16x32_bf16(aA[m][0], bB[n][0],
                                                             acc0[m][n], 0, 0, 0);
        acc0[m][n] = __builtin_amdgcn_mfma_f32_16x16x32_bf16(aA[m][1], bB[n][1],
                                                             acc0[m][n], 0, 0, 0);
      }
    __builtin_amdgcn_s_setprio(0);
#pragma unroll
    for (int m = 0; m < 4; ++m) {
      const int ra = (wr * 128 + 64 + m * 16 + l15) * 64;
      aA[m][0] = *reinterpret_cast<const short8*>(&Ab[ra + cp0]);
      aA[m][1] = *reinterpret_cast<const short8*>(&Ab[ra + cp1]);
    }
    __builtin_amdgcn_s_setprio(1);
#pragma unroll
    for (int m = 0; m < 4; ++m)
#pragma unroll
      for (int n = 0; n < 4; ++n) {
        acc1[m][n] = __builtin_amdgcn_mfma_f32_16x16x32_bf16(aA[m][0], bB[n][0],
                                                             acc1[m][n], 0, 0, 0);
        acc1[m][n] = __builtin_amdgcn_mfma_f32_16x16x32_bf16(aA[m][1], bB[n][1],
                                                             acc1[m][n], 0, 0, 0);
      }
    __builtin_amdgcn_s_setprio(0);

    if (kt + 1 < NT) {
      __builtin_amdgcn_s_barrier();
      if (kt + 2 < NT) {
        stage(kt + 2, kt & 1);
        asm volatile("s_waitcnt vmcnt(8)" ::: "memory");
      } else {
        asm volatile("s_waitcnt vmcnt(0)" ::: "memory");
      }
      __builtin_amdgcn_s_barrier();
    }
  }

#pragma unroll
  for (int mh = 0; mh < 2; ++mh) {
#pragma unroll
    for (int m = 0; m < 4; ++m) {
      const long r0 = brow + wr * 128 + mh * 64 + m * 16 + (lane >> 4) * 4;
#pragma unroll
      for (int n = 0; n < 4; ++n) {
        const long c0 = bcol + wc * 64 + n * 16 + l15;
        const f32x4 v = mh ? acc1[m][n] : acc0[m][n];
#pragma unroll
        for (int r = 0; r < 4; ++r) {
          if constexpr (sizeof(OutT) == 2)
            C[(r0 + r) * N + c0] = __float2bfloat16(v[r]);
          else
            C[(r0 + r) * N + c0] = v[r];
        }
      }
    }
  }
}

// ------- 256x128-tile bf16 GEMM (out-proj), counted-vmcnt pipeline ---------
__global__ __launch_bounds__(512, 1) void k_gemm_op(
    const bf16* __restrict__ A, const bf16* __restrict__ B,
    float* __restrict__ C, int M, int N, int K) {
  __shared__ bf16 Al[2][256 * 64];   // 64 KB
  __shared__ bf16 Bl[2][128 * 64];   // 32 KB
  const int tid = threadIdx.x;
  const int lane = tid & 63;
  const int wid = tid >> 6;
  const int wr = wid >> 1;
  const int wc = wid & 1;
  const int2 bxy = xcd_swz(gridDim.x);
  const long brow = (long)bxy.y * 256;
  const long bcol = (long)bxy.x * 128;
  const int NT = K >> 6;

  auto stage = [&](int kt, int buf) {
    const bf16* At = A + brow * K + kt * 64;
    const bf16* Bt = B + bcol * K + kt * 64;
#pragma unroll
    for (int i = 0; i < 4; ++i) {
      const int ch = tid + i * 512;
      const int row = ch >> 3;
      const int j = (ch & 7) ^ (row & 7);
      gld_lds16(At + (size_t)row * K + j * 8, &Al[buf][(wid * 64 + i * 512) * 8]);
    }
#pragma unroll
    for (int i = 0; i < 2; ++i) {
      const int ch = tid + i * 512;
      const int row = ch >> 3;
      const int j = (ch & 7) ^ (row & 7);
      gld_lds16(Bt + (size_t)row * K + j * 8, &Bl[buf][(wid * 64 + i * 512) * 8]);
    }
  };

  f32x4 acc[4][4];
#pragma unroll
  for (int m = 0; m < 4; ++m)
#pragma unroll
    for (int n = 0; n < 4; ++n) acc[m][n] = (f32x4){0.f, 0.f, 0.f, 0.f};

  const int l15 = lane & 15;
  const int cp0 = ((lane >> 4) ^ (lane & 7)) * 8;
  const int cp1 = ((4 + (lane >> 4)) ^ (lane & 7)) * 8;

  stage(0, 0);
  stage(1, 1);
  asm volatile("s_waitcnt vmcnt(6)" ::: "memory");
  __builtin_amdgcn_s_barrier();

  for (int kt = 0; kt < NT; ++kt) {
    const bf16* Ab = &Al[kt & 1][0];
    const bf16* Bb = &Bl[kt & 1][0];
    short8 bB[4][2], aA[4][2];
#pragma unroll
    for (int n = 0; n < 4; ++n) {
      const int rb = (wc * 64 + n * 16 + l15) * 64;
      bB[n][0] = *reinterpret_cast<const short8*>(&Bb[rb + cp0]);
      bB[n][1] = *reinterpret_cast<const short8*>(&Bb[rb + cp1]);
    }
#pragma unroll
    for (int m = 0; m < 4; ++m) {
      const int ra = (wr * 64 + m * 16 + l15) * 64;
      aA[m][0] = *reinterpret_cast<const short8*>(&Ab[ra + cp0]);
      aA[m][1] = *reinterpret_cast<const short8*>(&Ab[ra + cp1]);
    }
    __builtin_amdgcn_s_setprio(1);
#pragma unroll
    for (int m = 0; m < 4; ++m)
#pragma unroll
      for (int n = 0; n < 4; ++n) {
        acc[m][n] = __builtin_amdgcn_mfma_f32_16x16x32_bf16(aA[m][0], bB[n][0],
                                                            acc[m][n], 0, 0, 0);
        acc[m][n] = __builtin_amdgcn_mfma_f32_16x16x32_bf16(aA[m][1], bB[n][1],
                                                            acc[m][n], 0, 0, 0);
      }
    __builtin_amdgcn_s_setprio(0);

    if (kt + 1 < NT) {
      __builtin_amdgcn_s_barrier();
      if (kt + 2 < NT) {
        stage(kt + 2, kt & 1);
        asm volatile("s_waitcnt vmcnt(6)" ::: "memory");
      } else {
        asm volatile("s_waitcnt vmcnt(0)" ::: "memory");
      }
      __builtin_amdgcn_s_barrier();
    }
  }

#pragma unroll
  for (int m = 0; m < 4; ++m) {
    const long r0 = brow + wr * 64 + m * 16 + (lane >> 4) * 4;
#pragma unroll
    for (int n = 0; n < 4; ++n) {
      const long c0 = bcol + wc * 64 + n * 16 + l15;
#pragma unroll
      for (int r = 0; r < 4; ++r) C[(r0 + r) * N + c0] = acc[m][n][r];
    }
  }
}

// --- fused prep: RMSNorm+RoPE (q/k), V transpose, AND wo f32->bf16 cvt -----
// blocks [0,24576): normrope | [24576,25088): vt | [25088,27136): wo cvt
__global__ __launch_bounds__(256) void k_prep(
    const bf16* __restrict__ QKVb, const float* __restrict__ cosb,
    const float* __restrict__ sinb, const float* __restrict__ qw,
    const float* __restrict__ kw, const float* __restrict__ wo,
    bf16* __restrict__ Qb, bf16* __restrict__ Kb, bf16* __restrict__ Vt,
    bf16* __restrict__ Wo) {
  __shared__ bf16 Lds[64][136];
  const int tid = threadIdx.x;
  if (blockIdx.x < 24576) {
    // --- normrope: q/k rows only ---
    const int lane = tid & 63;
    const int u = blockIdx.x * 4 + (tid >> 6);
    const int s = u / 24;
    const int idx = u - s * 24;
    const bf16* src = QKVb + (size_t)s * 4096 + idx * 128;
    float x0 = __bfloat162float(src[lane]);
    float x1 = __bfloat162float(src[lane + 64]);
    float ss = x0 * x0 + x1 * x1;
#pragma unroll
    for (int off = 1; off < 64; off <<= 1) ss += __shfl_xor(ss, off);
    const float rn = rsqrtf(ss * (1.f / 128.f) + 1e-6f);
    const float* w = (idx < 16) ? qw : kw;
    x0 = x0 * rn * w[lane];
    x1 = x1 * rn * w[lane + 64];
    const float c0 = cosb[(size_t)s * 128 + lane];
    const float c1 = cosb[(size_t)s * 128 + lane + 64];
    const float s0 = sinb[(size_t)s * 128 + lane];
    const float s1 = sinb[(size_t)s * 128 + lane + 64];
    float o0 = x0 * c0 - x1 * s0;
    float o1 = x1 * c1 + x0 * s1;
    if (idx < 16) { o0 *= QSCALE; o1 *= QSCALE; }
    bf16* dst = (idx < 16) ? (Qb + ((size_t)idx * S_LEN + s) * 128)
                           : (Kb + ((size_t)(idx - 16) * S_LEN + s) * 128);
    dst[lane] = __float2bfloat16(o0);
    dst[lane + 64] = __float2bfloat16(o1);
  } else if (blockIdx.x < 25088) {
    // --- V transpose tile: v cols 3072.. -> Vt [KV][128][S] ---
    const int b = blockIdx.x - 24576;   // 0..511
    const int s0 = (b & 63) * 64;
    const int kv = b >> 6;
#pragma unroll
    for (int pass = 0; pass < 4; ++pass) {
      const int c = tid + pass * 256;
      const int r = c >> 4;
      const int off = (c & 15) * 8;
      *reinterpret_cast<short8*>(&Lds[r][off]) =
          *reinterpret_cast<const short8*>(
              &QKVb[(size_t)(s0 + r) * 4096 + 3072 + kv * 128 + off]);
    }
    __syncthreads();
#pragma unroll
    for (int pass = 0; pass < 4; ++pass) {
      const int c = tid + pass * 256;
      const int d = c >> 3;
      const int so = (c & 7) * 8;
      short8 o;
#pragma unroll
      for (int j = 0; j < 8; ++j) {
        bf16 e = Lds[so + j][d];
        o[j] = *reinterpret_cast<short*>(&e);
      }
      *reinterpret_cast<short8*>(&Vt[((size_t)kv * 128 + d) * S_LEN + s0 + so]) =
          o;
    }
  } else {
    // --- wo f32 -> bf16 ---
    const long u = (long)(blockIdx.x - 25088) * 256 + tid;  // 8-elem units
    const long i = u * 8;
    float4 a = *reinterpret_cast<const float4*>(wo + i);
    float4 b = *reinterpret_cast<const float4*>(wo + i + 4);
    float v[8] = {a.x, a.y, a.z, a.w, b.x, b.y, b.z, b.w};
    short8 o;
#pragma unroll
    for (int j = 0; j < 8; ++j) {
      bf16 h = __float2bfloat16(v[j]);
      o[j] = *reinterpret_cast<short*>(&h);
    }
    *reinterpret_cast<short8*>(Wo + i) = o;
  }
}

// ---------- causal flash attention, paired-prefix dual-q (GQA, D=128) -------
// Block handles q-tiles qlo=bx and qhi=63-bx in ONE KV loop over [0, 64-bx):
// K/V staged once; shared-prefix steps (t<=qlo) feed both subtiles from one
// kf read. kvh->XCD pinning kept; pairs (lin, lin+256) get (bx, 31-bx) so
// per-CU work is constant. LDS 72 KB -> 2 blocks/CU.
__global__ __launch_bounds__(256) void k_attn(const bf16* __restrict__ Qb,
                                              const bf16* __restrict__ Kb,
                                              const bf16* __restrict__ Vt_g,
                                              bf16* __restrict__ AO) {
  __shared__ bf16 Kl[2][64 * 128];   // [kv][d], chunk-swizzled, linear
  __shared__ bf16 Vl[2][128 * 64];   // [d][kv], chunk-swizzled, linear
  __shared__ bf16 Pl[4][16 * 64];    // P[q][kv], chunk-swizzled  (8 KB)
  const int tid = threadIdx.x;
  const int lane = tid & 63;
  const int wv = tid >> 6;
  // kvh->XCD pinning + balanced bx pairing
  const int lin = blockIdx.y * 32 + blockIdx.x;
  const int xcd = lin & 7;
  const int jj = lin >> 3;             // 0..63
  const int h = 2 * xcd + (jj & 1);    // kvh = xcd
  const int u = jj >> 1;               // 0..31
  const int bx = (u < 16) ? u : (47 - u);
  const int kvh = xcd;
  const int qlo = bx;
  const int NT = 64 - bx;              // tiles walked (qhi = 63-bx)
  const int c16 = lane & 15;
  const int hi = lane >> 4;
  const int kk = hi * 8;

  const bf16* Kbase = Kb + (size_t)kvh * S_LEN * 128;
  const bf16* Vbase = Vt_g + (size_t)kvh * 128 * S_LEN;

  auto stage = [&](int t, int buf) {
    const bf16* Kt = Kbase + (size_t)t * 64 * 128;
    const bf16* Vt = Vbase + t * 64;
#pragma unroll
    for (int p = 0; p < 4; ++p) {
      const int ch = tid + p * 256;
      const int row = ch >> 4, cp = ch & 15;
      const int c = (cp & 8) | ((cp & 7) ^ (row & 7));
      gld_lds16(Kt + row * 128 + c * 8, &Kl[buf][(wv * 64 + p * 256) * 8]);
    }
#pragma unroll
    for (int p = 0; p < 4; ++p) {
      const int ch = tid + p * 256;
      const int d = ch >> 3, cp = ch & 7;
      const int c = cp ^ (d & 7);
      gld_lds16(Vt + (size_t)d * S_LEN + c * 8, &Vl[buf][(wv * 64 + p * 256) * 8]);
    }
  };

  const int growA = qlo * 64 + wv * 16 + c16;
  const int growB = (63 - bx) * 64 + wv * 16 + c16;

  short8 qfA[4], qfB[4];
  {
    const bf16* qpA = Qb + ((size_t)h * S_LEN + growA) * 128 + kk;
    const bf16* qpB = Qb + ((size_t)h * S_LEN + growB) * 128 + kk;
#pragma unroll
    for (int ks = 0; ks < 4; ++ks) {
      qfA[ks] = *reinterpret_cast<const short8*>(qpA + ks * 32);
      qfB[ks] = *reinterpret_cast<const short8*>(qpB + ks * 32);
    }
  }

  f32x4 oA[8], oB[8];
#pragma unroll
  for (int i = 0; i < 8; ++i) {
    oA[i] = (f32x4){0.f, 0.f, 0.f, 0.f};
    oB[i] = (f32x4){0.f, 0.f, 0.f, 0.f};
  }
  float mA = -1e30f, mB = -1e30f, lA = 0.f, lB = 0.f;

  stage(0, 0);
  __syncthreads();  // tile 0 staged

  int cur = 0;
  for (int t = 0; t < NT; ++t) {
    if (t + 1 < NT) stage(t + 1, cur ^ 1);
    const bool activeA = (t <= qlo);
    const bool maskA = (t == qlo);
    const bool maskB = (t == NT - 1);

    // QK^T: kf read ONCE feeds both subtiles on the shared prefix
    f32x4 sA[4], sB[4];
#pragma unroll
    for (int nt = 0; nt < 4; ++nt) {
      sA[nt] = (f32x4){0.f, 0.f, 0.f, 0.f};
      sB[nt] = (f32x4){0.f, 0.f, 0.f, 0.f};
    }
    __builtin_amdgcn_s_setprio(1);
#pragma unroll
    for (int ks = 0; ks < 4; ++ks) {
#pragma unroll
      for (int nt = 0; nt < 4; ++nt) {
        const int row = nt * 16 + c16;
        const int ck = ks * 4 + hi;
        const int ckp = (ck & 8) | ((ck & 7) ^ (row & 7));
        short8 kf =
            *reinterpret_cast<const short8*>(&Kl[cur][row * 128 + ckp * 8]);
        if (activeA)
          sA[nt] = __builtin_amdgcn_mfma_f32_16x16x32_bf16(kf, qfA[ks], sA[nt],
                                                           0, 0, 0);
        sB[nt] = __builtin_amdgcn_mfma_f32_16x16x32_bf16(kf, qfB[ks], sB[nt],
                                                         0, 0, 0);
      }
    }
    __builtin_amdgcn_s_setprio(0);

    // ---- subtile A: softmax + P + PV ----
    if (activeA) {
      float tm = -1e30f;
#pragma unroll
      for (int nt = 0; nt < 4; ++nt)
#pragma unroll
        for (int r = 0; r < 4; ++r) {
          float sv = sA[nt][r];
          if (maskA && (t * 64 + nt * 16 + 4 * hi + r > growA)) sv = -1e30f;
          sA[nt][r] = sv;
          tm = fmaxf(tm, sv);
        }
      tm = fmaxf(tm, __shfl_xor(tm, 16));
      tm = fmaxf(tm, __shfl_xor(tm, 32));
      if (__any(tm > mA + 8.f)) {
        const float mn = fmaxf(mA, tm);
        const float alpha = fexp2(mA - mn);
        mA = mn;
        lA *= alpha;
#pragma unroll
        for (int dn = 0; dn < 8; ++dn) oA[dn] *= alpha;
      }
#pragma unroll
      for (int nt = 0; nt < 4; ++nt) {
        const float p0 = fexp2(sA[nt][0] - mA);
        const float p1 = fexp2(sA[nt][1] - mA);
        const float p2 = fexp2(sA[nt][2] - mA);
        const float p3 = fexp2(sA[nt][3] - mA);
        lA += (p0 + p1) + (p2 + p3);
        uint2 w2;
        w2.x = cvtpk_bf16(p0, p1);
        w2.y = cvtpk_bf16(p2, p3);
        const int chunk = (2 * nt + (hi >> 1)) ^ (c16 & 7);
        const int base = c16 * 64 + chunk * 8 + 4 * (hi & 1);
        *reinterpret_cast<uint2*>(&Pl[wv][base]) = w2;
      }
      __builtin_amdgcn_s_setprio(1);
#pragma unroll
      for (int ks = 0; ks < 2; ++ks) {
        const int pc = (ks * 4 + hi) ^ (c16 & 7);
        short8 pf =
            *reinterpret_cast<const short8*>(&Pl[wv][c16 * 64 + pc * 8]);
#pragma unroll
        for (int dn = 0; dn < 8; ++dn) {
          const int d = dn * 16 + c16;
          const int cvp = (ks * 4 + hi) ^ (d & 7);
          short8 vf =
              *reinterpret_cast<const short8*>(&Vl[cur][d * 64 + cvp * 8]);
          oA[dn] = __builtin_amdgcn_mfma_f32_16x16x32_bf16(vf, pf, oA[dn],
                                                           0, 0, 0);
        }
      }
      __builtin_amdgcn_s_setprio(0);
    }

    // ---- subtile B: softmax + P + PV ----
    {
      float tm = -1e30f;
#pragma unroll
      for (int nt = 0; nt < 4; ++nt)
#pragma unroll
        for (int r = 0; r < 4; ++r) {
          float sv = sB[nt][r];
          if (maskB && (t * 64 + nt * 16 + 4 * hi + r > growB)) sv = -1e30f;
          sB[nt][r] = sv;
          tm = fmaxf(tm, sv);
        }
      tm = fmaxf(tm, __shfl_xor(tm, 16));
      tm = fmaxf(tm, __shfl_xor(tm, 32));
      if (__any(tm > mB + 8.f)) {
        const float mn = fmaxf(mB, tm);
        const float alpha = fexp2(mB - mn);
        mB = mn;
        lB *= alpha;
#pragma unroll
        for (int dn = 0; dn < 8; ++dn) oB[dn] *= alpha;
      }
#pragma unroll
      for (int nt = 0; nt < 4; ++nt) {
        const float p0 = fexp2(sB[nt][0] - mB);
        const float p1 = fexp2(sB[nt][1] - mB);
        const float p2 = fexp2(sB[nt][2] - mB);
        const float p3 = fexp2(sB[nt][3] - mB);
        lB += (p0 + p1) + (p2 + p3);
        uint2 w2;
        w2.x = cvtpk_bf16(p0, p1);
        w2.y = cvtpk_bf16(p2, p3);
        const int chunk = (2 * nt + (hi >> 1)) ^ (c16 & 7);
        const int base = c16 * 64 + chunk * 8 + 4 * (hi & 1);
        *reinterpret_cast<uint2*>(&Pl[wv][base]) = w2;
      }
      __builtin_amdgcn_s_setprio(1);
#pragma unroll
      for (int ks = 0; ks < 2; ++ks) {
        const int pc = (ks * 4 + hi) ^ (c16 & 7);
        short8 pf =
            *reinterpret_cast<const short8*>(&Pl[wv][c16 * 64 + pc * 8]);
#pragma unroll
        for (int dn = 0; dn < 8; ++dn) {
          const int d = dn * 16 + c16;
          const int cvp = (ks * 4 + hi) ^ (d & 7);
          short8 vf =
              *reinterpret_cast<const short8*>(&Vl[cur][d * 64 + cvp * 8]);
          oB[dn] = __builtin_amdgcn_mfma_f32_16x16x32_bf16(vf, pf, oB[dn],
                                                           0, 0, 0);
        }
      }
      __builtin_amdgcn_s_setprio(0);
    }

    if (t + 1 < NT) {
      __syncthreads();  // drains stage loads; all waves done reading cur
      cur ^= 1;
    }
  }

  // epilogue: normalize and write both subtiles (pair-packed b32)
  {
    float lt = lA;
    lt += __shfl_xor(lt, 16);
    lt += __shfl_xor(lt, 32);
    const float inv = 1.f / lt;
    bf16* dst = AO + (size_t)growA * HID_DIM + h * 128;
#pragma unroll
    for (int dn = 0; dn < 8; ++dn)
#pragma unroll
      for (int w = 0; w < 2; ++w) {
        const unsigned pk =
            cvtpk_bf16(oA[dn][2 * w] * inv, oA[dn][2 * w + 1] * inv);
        *reinterpret_cast<unsigned*>(&dst[dn * 16 + 4 * hi + 2 * w]) = pk;
      }
  }
  {
    float lt = lB;
    lt += __shfl_xor(lt, 16);
    lt += __shfl_xor(lt, 32);
    const float inv = 1.f / lt;
    bf16* dst = AO + (size_t)growB * HID_DIM + h * 128;
#pragma unroll
    for (int dn = 0; dn < 8; ++dn)
#pragma unroll
      for (int w = 0; w < 2; ++w) {
        const unsigned pk =
            cvtpk_bf16(oB[dn][2 * w] * inv, oB[dn][2 * w + 1] * inv);
        *reinterpret_cast<unsigned*>(&dst[dn * 16 + 4 * hi + 2 * w]) = pk;
      }
  }
}

extern "C" void kernel_launch(void* const* d_in, const int* in_sizes, int n_in,
                              void* d_out, int out_size, void* d_ws,
                              size_t ws_size, hipStream_t stream) {
  (void)in_sizes; (void)n_in; (void)out_size; (void)ws_size;
  const float* hs = (const float*)d_in[0];
  const float* cosb = (const float*)d_in[1];
  const float* sinb = (const float*)d_in[2];
  const float* wq = (const float*)d_in[3];
  const float* wk = (const float*)d_in[4];
  const float* wv = (const float*)d_in[5];
  const float* wo = (const float*)d_in[6];
  const float* qnw = (const float*)d_in[7];
  const float* knw = (const float*)d_in[8];
  float* out = (float*)d_out;
  char* ws = (char*)d_ws;

  bf16* Ah = (bf16*)(ws + 0);              // hidden bf16        16.78 MB
  bf16* Wqkv = (bf16*)(ws + 16777216);     // packed qkv weights 16.78 MB
  bf16* Wo = (bf16*)(ws + 33554432);       // wo bf16             8.39 MB
  bf16* QKVb = (bf16*)(ws + 41943040);     // qkv proj bf16      33.55 MB
  bf16* Qb = (bf16*)(ws + 75497472);       // Q [H][S][D]        16.78 MB
  bf16* Kb = (bf16*)(ws + 92274688);       // K [KV][S][D]        8.39 MB
  bf16* AO = (bf16*)(ws + 109051904);      // attn out [S][H*D]  16.78 MB
  bf16* Vt = (bf16*)(ws + 125829120);      // V^T [KV][128][S]    8.39 MB

  k_cvt4<<<dim3(8192), dim3(256), 0, stream>>>(hs, wq, wk, wv, Ah, Wqkv);
  k_gemm256<bf16><<<dim3(16, 16), dim3(512), 0, stream>>>(Ah, Wqkv, QKVb, 4096,
                                                          4096, 2048);
  k_prep<<<dim3(27136), dim3(256), 0, stream>>>(QKVb, cosb, sinb, qnw, knw, wo,
                                                Qb, Kb, Vt, Wo);
  k_attn<<<dim3(32, 16), dim3(256), 0, stream>>>(Qb, Kb, Vt, AO);
  k_gemm_op<<<dim3(16, 16), dim3(512), 0, stream>>>(AO, Wo, out, 4096, 2048,
                                                    2048);
}

// Round 26
// 252.728 us; speedup vs baseline: 1.5622x; 1.5622x over previous
//
#include <hip/hip_runtime.h>
#include <hip/hip_bf16.h>

typedef __hip_bfloat16 bf16;
typedef __attribute__((ext_vector_type(8))) short short8;
typedef __attribute__((ext_vector_type(4))) float f32x4;

#define S_LEN 4096
#define HID_DIM 2048

// 1/sqrt(128) * log2(e): folded into Q so softmax runs in exp2 domain
#define QSCALE ((float)(0.08838834764831845 * 1.4426950408889634))

__device__ __forceinline__ void gld_lds16(const void* g, void* l) {
  __builtin_amdgcn_global_load_lds(
      (const __attribute__((address_space(1))) void*)g,
      (__attribute__((address_space(3))) void*)l, 16, 0, 0);
}

__device__ __forceinline__ float fexp2(float x) {
  return __builtin_amdgcn_exp2f(x);  // bare v_exp_f32
}

__device__ __forceinline__ unsigned cvtpk_bf16(float lo, float hi) {
  unsigned r;
  asm("v_cvt_pk_bf16_f32 %0, %1, %2" : "=v"(r) : "v"(lo), "v"(hi));
  return r;
}

// ---------------- fused fp32 -> bf16 convert (hs, wq, wk, wv) ----------------
__global__ __launch_bounds__(256) void k_cvt4(
    const float* __restrict__ hs, const float* __restrict__ wq,
    const float* __restrict__ wk, const float* __restrict__ wv,
    bf16* __restrict__ Ah, bf16* __restrict__ Wqkv) {
  long u = (long)blockIdx.x * 256 + threadIdx.x;  // 8-elem unit index
  const float* src;
  bf16* dst;
  if (u < 1048576) {
    src = hs; dst = Ah;
  } else if (u < 1572864) {
    u -= 1048576; src = wq; dst = Wqkv;
  } else if (u < 1835008) {
    u -= 1572864; src = wk; dst = Wqkv + (long)2048 * 2048;
  } else {
    u -= 1835008; src = wv; dst = Wqkv + (long)3072 * 2048;
  }
  const long i = u * 8;
  float4 a = *reinterpret_cast<const float4*>(src + i);
  float4 b = *reinterpret_cast<const float4*>(src + i + 4);
  float v[8] = {a.x, a.y, a.z, a.w, b.x, b.y, b.z, b.w};
  short8 o;
#pragma unroll
  for (int j = 0; j < 8; ++j) {
    bf16 h = __float2bfloat16(v[j]);
    o[j] = *reinterpret_cast<short*>(&h);
  }
  *reinterpret_cast<short8*>(dst + i) = o;
}

// bijective XCD swizzle for nwg % 8 == 0 (T1, m204)
__device__ __forceinline__ int2 xcd_swz(int nx) {
  const int bid = blockIdx.y * nx + blockIdx.x;
  const int nwg = nx * gridDim.y;
  const int q = nwg >> 3;
  const int swz = (bid & 7) * q + (bid >> 3);
  return make_int2(swz % nx, swz / nx);
}

// ------- 256^2-tile bf16 GEMM, C = A * B^T, counted-vmcnt pipeline ---------
template <typename OutT>
__global__ __launch_bounds__(512, 1) void k_gemm256(
    const bf16* __restrict__ A, const bf16* __restrict__ B,
    OutT* __restrict__ C, int M, int N, int K) {
  __shared__ bf16 Al[2][256 * 64];   // 64 KB
  __shared__ bf16 Bl[2][256 * 64];   // 64 KB
  const int tid = threadIdx.x;
  const int lane = tid & 63;
  const int wid = tid >> 6;
  const int wr = wid >> 2;
  const int wc = wid & 3;
  const int2 bxy = xcd_swz(gridDim.x);
  const long brow = (long)bxy.y * 256;
  const long bcol = (long)bxy.x * 256;
  const int NT = K >> 6;

  auto stage = [&](int kt, int buf) {
    const bf16* At = A + brow * K + kt * 64;
    const bf16* Bt = B + bcol * K + kt * 64;
#pragma unroll
    for (int i = 0; i < 4; ++i) {
      const int ch = tid + i * 512;
      const int row = ch >> 3;
      const int j = (ch & 7) ^ (row & 7);
      gld_lds16(At + (size_t)row * K + j * 8, &Al[buf][(wid * 64 + i * 512) * 8]);
    }
#pragma unroll
    for (int i = 0; i < 4; ++i) {
      const int ch = tid + i * 512;
      const int row = ch >> 3;
      const int j = (ch & 7) ^ (row & 7);
      gld_lds16(Bt + (size_t)row * K + j * 8, &Bl[buf][(wid * 64 + i * 512) * 8]);
    }
  };

  f32x4 acc0[4][4], acc1[4][4];
#pragma unroll
  for (int m = 0; m < 4; ++m)
#pragma unroll
    for (int n = 0; n < 4; ++n) {
      acc0[m][n] = (f32x4){0.f, 0.f, 0.f, 0.f};
      acc1[m][n] = (f32x4){0.f, 0.f, 0.f, 0.f};
    }

  const int l15 = lane & 15;
  const int cp0 = ((lane >> 4) ^ (lane & 7)) * 8;
  const int cp1 = ((4 + (lane >> 4)) ^ (lane & 7)) * 8;

  stage(0, 0);
  stage(1, 1);
  asm volatile("s_waitcnt vmcnt(8)" ::: "memory");
  __builtin_amdgcn_s_barrier();

  for (int kt = 0; kt < NT; ++kt) {
    const bf16* Ab = &Al[kt & 1][0];
    const bf16* Bb = &Bl[kt & 1][0];
    short8 bB[4][2], aA[4][2];
#pragma unroll
    for (int n = 0; n < 4; ++n) {
      const int rb = (wc * 64 + n * 16 + l15) * 64;
      bB[n][0] = *reinterpret_cast<const short8*>(&Bb[rb + cp0]);
      bB[n][1] = *reinterpret_cast<const short8*>(&Bb[rb + cp1]);
    }
#pragma unroll
    for (int m = 0; m < 4; ++m) {
      const int ra = (wr * 128 + m * 16 + l15) * 64;
      aA[m][0] = *reinterpret_cast<const short8*>(&Ab[ra + cp0]);
      aA[m][1] = *reinterpret_cast<const short8*>(&Ab[ra + cp1]);
    }
    __builtin_amdgcn_s_setprio(1);
#pragma unroll
    for (int m = 0; m < 4; ++m)
#pragma unroll
      for (int n = 0; n < 4; ++n) {
        acc0[m][n] = __builtin_amdgcn_mfma_f32_16x16x32_bf16(aA[m][0], bB[n][0],
                                                             acc0[m][n], 0, 0, 0);
        acc0[m][n] = __builtin_amdgcn_mfma_f32_16x16x32_bf16(aA[m][1], bB[n][1],
                                                             acc0[m][n], 0, 0, 0);
      }
    __builtin_amdgcn_s_setprio(0);
#pragma unroll
    for (int m = 0; m < 4; ++m) {
      const int ra = (wr * 128 + 64 + m * 16 + l15) * 64;
      aA[m][0] = *reinterpret_cast<const short8*>(&Ab[ra + cp0]);
      aA[m][1] = *reinterpret_cast<const short8*>(&Ab[ra + cp1]);
    }
    __builtin_amdgcn_s_setprio(1);
#pragma unroll
    for (int m = 0; m < 4; ++m)
#pragma unroll
      for (int n = 0; n < 4; ++n) {
        acc1[m][n] = __builtin_amdgcn_mfma_f32_16x16x32_bf16(aA[m][0], bB[n][0],
                                                             acc1[m][n], 0, 0, 0);
        acc1[m][n] = __builtin_amdgcn_mfma_f32_16x16x32_bf16(aA[m][1], bB[n][1],
                                                             acc1[m][n], 0, 0, 0);
      }
    __builtin_amdgcn_s_setprio(0);

    if (kt + 1 < NT) {
      __builtin_amdgcn_s_barrier();
      if (kt + 2 < NT) {
        stage(kt + 2, kt & 1);
        asm volatile("s_waitcnt vmcnt(8)" ::: "memory");
      } else {
        asm volatile("s_waitcnt vmcnt(0)" ::: "memory");
      }
      __builtin_amdgcn_s_barrier();
    }
  }

#pragma unroll
  for (int mh = 0; mh < 2; ++mh) {
#pragma unroll
    for (int m = 0; m < 4; ++m) {
      const long r0 = brow + wr * 128 + mh * 64 + m * 16 + (lane >> 4) * 4;
#pragma unroll
      for (int n = 0; n < 4; ++n) {
        const long c0 = bcol + wc * 64 + n * 16 + l15;
        const f32x4 v = mh ? acc1[m][n] : acc0[m][n];
#pragma unroll
        for (int r = 0; r < 4; ++r) {
          if constexpr (sizeof(OutT) == 2)
            C[(r0 + r) * N + c0] = __float2bfloat16(v[r]);
          else
            C[(r0 + r) * N + c0] = v[r];
        }
      }
    }
  }
}

// ------- 256x128-tile bf16 GEMM (out-proj), counted-vmcnt pipeline ---------
__global__ __launch_bounds__(512, 1) void k_gemm_op(
    const bf16* __restrict__ A, const bf16* __restrict__ B,
    float* __restrict__ C, int M, int N, int K) {
  __shared__ bf16 Al[2][256 * 64];   // 64 KB
  __shared__ bf16 Bl[2][128 * 64];   // 32 KB
  const int tid = threadIdx.x;
  const int lane = tid & 63;
  const int wid = tid >> 6;
  const int wr = wid >> 1;
  const int wc = wid & 1;
  const int2 bxy = xcd_swz(gridDim.x);
  const long brow = (long)bxy.y * 256;
  const long bcol = (long)bxy.x * 128;
  const int NT = K >> 6;

  auto stage = [&](int kt, int buf) {
    const bf16* At = A + brow * K + kt * 64;
    const bf16* Bt = B + bcol * K + kt * 64;
#pragma unroll
    for (int i = 0; i < 4; ++i) {
      const int ch = tid + i * 512;
      const int row = ch >> 3;
      const int j = (ch & 7) ^ (row & 7);
      gld_lds16(At + (size_t)row * K + j * 8, &Al[buf][(wid * 64 + i * 512) * 8]);
    }
#pragma unroll
    for (int i = 0; i < 2; ++i) {
      const int ch = tid + i * 512;
      const int row = ch >> 3;
      const int j = (ch & 7) ^ (row & 7);
      gld_lds16(Bt + (size_t)row * K + j * 8, &Bl[buf][(wid * 64 + i * 512) * 8]);
    }
  };

  f32x4 acc[4][4];
#pragma unroll
  for (int m = 0; m < 4; ++m)
#pragma unroll
    for (int n = 0; n < 4; ++n) acc[m][n] = (f32x4){0.f, 0.f, 0.f, 0.f};

  const int l15 = lane & 15;
  const int cp0 = ((lane >> 4) ^ (lane & 7)) * 8;
  const int cp1 = ((4 + (lane >> 4)) ^ (lane & 7)) * 8;

  stage(0, 0);
  stage(1, 1);
  asm volatile("s_waitcnt vmcnt(6)" ::: "memory");
  __builtin_amdgcn_s_barrier();

  for (int kt = 0; kt < NT; ++kt) {
    const bf16* Ab = &Al[kt & 1][0];
    const bf16* Bb = &Bl[kt & 1][0];
    short8 bB[4][2], aA[4][2];
#pragma unroll
    for (int n = 0; n < 4; ++n) {
      const int rb = (wc * 64 + n * 16 + l15) * 64;
      bB[n][0] = *reinterpret_cast<const short8*>(&Bb[rb + cp0]);
      bB[n][1] = *reinterpret_cast<const short8*>(&Bb[rb + cp1]);
    }
#pragma unroll
    for (int m = 0; m < 4; ++m) {
      const int ra = (wr * 64 + m * 16 + l15) * 64;
      aA[m][0] = *reinterpret_cast<const short8*>(&Ab[ra + cp0]);
      aA[m][1] = *reinterpret_cast<const short8*>(&Ab[ra + cp1]);
    }
    __builtin_amdgcn_s_setprio(1);
#pragma unroll
    for (int m = 0; m < 4; ++m)
#pragma unroll
      for (int n = 0; n < 4; ++n) {
        acc[m][n] = __builtin_amdgcn_mfma_f32_16x16x32_bf16(aA[m][0], bB[n][0],
                                                            acc[m][n], 0, 0, 0);
        acc[m][n] = __builtin_amdgcn_mfma_f32_16x16x32_bf16(aA[m][1], bB[n][1],
                                                            acc[m][n], 0, 0, 0);
      }
    __builtin_amdgcn_s_setprio(0);

    if (kt + 1 < NT) {
      __builtin_amdgcn_s_barrier();
      if (kt + 2 < NT) {
        stage(kt + 2, kt & 1);
        asm volatile("s_waitcnt vmcnt(6)" ::: "memory");
      } else {
        asm volatile("s_waitcnt vmcnt(0)" ::: "memory");
      }
      __builtin_amdgcn_s_barrier();
    }
  }

#pragma unroll
  for (int m = 0; m < 4; ++m) {
    const long r0 = brow + wr * 64 + m * 16 + (lane >> 4) * 4;
#pragma unroll
    for (int n = 0; n < 4; ++n) {
      const long c0 = bcol + wc * 64 + n * 16 + l15;
#pragma unroll
      for (int r = 0; r < 4; ++r) C[(r0 + r) * N + c0] = acc[m][n][r];
    }
  }
}

// --- fused prep: RMSNorm+RoPE (q/k), V transpose, AND wo f32->bf16 cvt -----
// blocks [0,24576): normrope | [24576,25088): vt | [25088,27136): wo cvt
__global__ __launch_bounds__(256) void k_prep(
    const bf16* __restrict__ QKVb, const float* __restrict__ cosb,
    const float* __restrict__ sinb, const float* __restrict__ qw,
    const float* __restrict__ kw, const float* __restrict__ wo,
    bf16* __restrict__ Qb, bf16* __restrict__ Kb, bf16* __restrict__ Vt,
    bf16* __restrict__ Wo) {
  __shared__ bf16 Lds[64][136];
  const int tid = threadIdx.x;
  if (blockIdx.x < 24576) {
    // --- normrope: q/k rows only ---
    const int lane = tid & 63;
    const int u = blockIdx.x * 4 + (tid >> 6);
    const int s = u / 24;
    const int idx = u - s * 24;
    const bf16* src = QKVb + (size_t)s * 4096 + idx * 128;
    float x0 = __bfloat162float(src[lane]);
    float x1 = __bfloat162float(src[lane + 64]);
    float ss = x0 * x0 + x1 * x1;
#pragma unroll
    for (int off = 1; off < 64; off <<= 1) ss += __shfl_xor(ss, off);
    const float rn = rsqrtf(ss * (1.f / 128.f) + 1e-6f);
    const float* w = (idx < 16) ? qw : kw;
    x0 = x0 * rn * w[lane];
    x1 = x1 * rn * w[lane + 64];
    const float c0 = cosb[(size_t)s * 128 + lane];
    const float c1 = cosb[(size_t)s * 128 + lane + 64];
    const float s0 = sinb[(size_t)s * 128 + lane];
    const float s1 = sinb[(size_t)s * 128 + lane + 64];
    float o0 = x0 * c0 - x1 * s0;
    float o1 = x1 * c1 + x0 * s1;
    if (idx < 16) { o0 *= QSCALE; o1 *= QSCALE; }
    bf16* dst = (idx < 16) ? (Qb + ((size_t)idx * S_LEN + s) * 128)
                           : (Kb + ((size_t)(idx - 16) * S_LEN + s) * 128);
    dst[lane] = __float2bfloat16(o0);
    dst[lane + 64] = __float2bfloat16(o1);
  } else if (blockIdx.x < 25088) {
    // --- V transpose tile: v cols 3072.. -> Vt [KV][128][S] ---
    const int b = blockIdx.x - 24576;   // 0..511
    const int s0 = (b & 63) * 64;
    const int kv = b >> 6;
#pragma unroll
    for (int pass = 0; pass < 4; ++pass) {
      const int c = tid + pass * 256;
      const int r = c >> 4;
      const int off = (c & 15) * 8;
      *reinterpret_cast<short8*>(&Lds[r][off]) =
          *reinterpret_cast<const short8*>(
              &QKVb[(size_t)(s0 + r) * 4096 + 3072 + kv * 128 + off]);
    }
    __syncthreads();
#pragma unroll
    for (int pass = 0; pass < 4; ++pass) {
      const int c = tid + pass * 256;
      const int d = c >> 3;
      const int so = (c & 7) * 8;
      short8 o;
#pragma unroll
      for (int j = 0; j < 8; ++j) {
        bf16 e = Lds[so + j][d];
        o[j] = *reinterpret_cast<short*>(&e);
      }
      *reinterpret_cast<short8*>(&Vt[((size_t)kv * 128 + d) * S_LEN + s0 + so]) =
          o;
    }
  } else {
    // --- wo f32 -> bf16 ---
    const long u = (long)(blockIdx.x - 25088) * 256 + tid;  // 8-elem units
    const long i = u * 8;
    float4 a = *reinterpret_cast<const float4*>(wo + i);
    float4 b = *reinterpret_cast<const float4*>(wo + i + 4);
    float v[8] = {a.x, a.y, a.z, a.w, b.x, b.y, b.z, b.w};
    short8 o;
#pragma unroll
    for (int j = 0; j < 8; ++j) {
      bf16 h = __float2bfloat16(v[j]);
      o[j] = *reinterpret_cast<short*>(&h);
    }
    *reinterpret_cast<short8*>(Wo + i) = o;
  }
}

// ---------------- causal flash attention (GQA 16q/8kv, D=128) ----------------
// R11/R17 structure + kvh->XCD pinning + T5 setprio + packed b64 P-writes.
__global__ __launch_bounds__(256) void k_attn(const bf16* __restrict__ Qb,
                                              const bf16* __restrict__ Kb,
                                              const bf16* __restrict__ Vt_g,
                                              bf16* __restrict__ AO) {
  __shared__ bf16 Kl[2][64 * 128];   // [kv][d], chunk-swizzled, linear
  __shared__ bf16 Vl[2][128 * 64];   // [d][kv], chunk-swizzled, linear
  __shared__ bf16 Pl[4][16 * 64];    // P[q][kv], chunk-swizzled  (8 KB)
  const int tid = threadIdx.x;
  const int lane = tid & 63;
  const int wv = tid >> 6;
  // kvh->XCD bijective remap of (blockIdx.x, blockIdx.y) in grid (32, 16)
  const int lin = blockIdx.y * 32 + blockIdx.x;
  const int xcd = lin & 7;
  const int jj = lin >> 3;           // 0..63
  const int h = 2 * xcd + (jj & 1);  // kvh = h>>1 = xcd
  const int bx = jj >> 1;            // 0..31
  const int kvh = h >> 1;
  const int c16 = lane & 15;
  const int hi = lane >> 4;
  const int kk = hi * 8;

  const bf16* Kbase = Kb + (size_t)kvh * S_LEN * 128;
  const bf16* Vbase = Vt_g + (size_t)kvh * 128 * S_LEN;

  auto stage = [&](int t, int buf) {
    const bf16* Kt = Kbase + (size_t)t * 64 * 128;
    const bf16* Vt = Vbase + t * 64;
#pragma unroll
    for (int p = 0; p < 4; ++p) {
      const int ch = tid + p * 256;
      const int row = ch >> 4, cp = ch & 15;
      const int c = (cp & 8) | ((cp & 7) ^ (row & 7));
      gld_lds16(Kt + row * 128 + c * 8, &Kl[buf][(wv * 64 + p * 256) * 8]);
    }
#pragma unroll
    for (int p = 0; p < 4; ++p) {
      const int ch = tid + p * 256;
      const int d = ch >> 3, cp = ch & 7;
      const int c = cp ^ (d & 7);
      gld_lds16(Vt + (size_t)d * S_LEN + c * 8, &Vl[buf][(wv * 64 + p * 256) * 8]);
    }
  };

  for (int half = 0; half < 2; ++half) {
    const int qt = half ? (63 - bx) : bx;
    const int qrow = qt * 64 + wv * 16;
    const int grow = qrow + c16;        // this lane's global q row

    __syncthreads();
    stage(0, 0);

    short8 qf[4];
    {
      const bf16* qp = Qb + ((size_t)h * S_LEN + grow) * 128 + kk;
#pragma unroll
      for (int ks = 0; ks < 4; ++ks)
        qf[ks] = *reinterpret_cast<const short8*>(qp + ks * 32);
    }

    f32x4 oacc[8];
#pragma unroll
    for (int i = 0; i < 8; ++i) oacc[i] = (f32x4){0.f, 0.f, 0.f, 0.f};
    float m_run = -1e30f;
    float l_part = 0.f;

    auto tile = [&](int t, int buf, bool mask) {
      // S^T = K Q^T: sacc[nt] reg r -> kv = t*64 + nt*16 + 4*hi + r, q = c16
      f32x4 sacc[4];
#pragma unroll
      for (int nt = 0; nt < 4; ++nt) sacc[nt] = (f32x4){0.f, 0.f, 0.f, 0.f};
      __builtin_amdgcn_s_setprio(1);
#pragma unroll
      for (int ks = 0; ks < 4; ++ks) {
#pragma unroll
        for (int nt = 0; nt < 4; ++nt) {
          const int row = nt * 16 + c16;
          const int ck = ks * 4 + hi;
          const int ckp = (ck & 8) | ((ck & 7) ^ (row & 7));
          short8 kf =
              *reinterpret_cast<const short8*>(&Kl[buf][row * 128 + ckp * 8]);
          sacc[nt] = __builtin_amdgcn_mfma_f32_16x16x32_bf16(kf, qf[ks],
                                                             sacc[nt], 0, 0, 0);
        }
      }
      __builtin_amdgcn_s_setprio(0);

      // lane-local softmax (q = c16): mask + max tree + 2 shfl reduce
      float tm = -1e30f;
#pragma unroll
      for (int nt = 0; nt < 4; ++nt)
#pragma unroll
        for (int r = 0; r < 4; ++r) {
          float sv = sacc[nt][r];
          if (mask && (t * 64 + nt * 16 + 4 * hi + r > grow)) sv = -1e30f;
          sacc[nt][r] = sv;
          tm = fmaxf(tm, sv);
        }
      tm = fmaxf(tm, __shfl_xor(tm, 16));
      tm = fmaxf(tm, __shfl_xor(tm, 32));
      if (__any(tm > m_run + 8.f)) {
        const float mn = fmaxf(m_run, tm);
        const float alpha = fexp2(m_run - mn);
        m_run = mn;
        l_part *= alpha;
#pragma unroll
        for (int dn = 0; dn < 8; ++dn) oacc[dn] *= alpha;
      }

      // exp + pack 4 values into one b64 LDS write (chunk-swizzled by q&7)
#pragma unroll
      for (int nt = 0; nt < 4; ++nt) {
        const float p0 = fexp2(sacc[nt][0] - m_run);
        const float p1 = fexp2(sacc[nt][1] - m_run);
        const float p2 = fexp2(sacc[nt][2] - m_run);
        const float p3 = fexp2(sacc[nt][3] - m_run);
        l_part += (p0 + p1) + (p2 + p3);
        uint2 w2;
        w2.x = cvtpk_bf16(p0, p1);
        w2.y = cvtpk_bf16(p2, p3);
        const int chunk = (2 * nt + (hi >> 1)) ^ (c16 & 7);
        const int base = c16 * 64 + chunk * 8 + 4 * (hi & 1);
        *reinterpret_cast<uint2*>(&Pl[wv][base]) = w2;
      }

      // O^T += V^T P^T: oacc[dn] reg r -> d = dn*16 + 4*hi + r, q = c16
      __builtin_amdgcn_s_setprio(1);
#pragma unroll
      for (int ks = 0; ks < 2; ++ks) {
        const int pc = (ks * 4 + hi) ^ (c16 & 7);
        short8 pf =
            *reinterpret_cast<const short8*>(&Pl[wv][c16 * 64 + pc * 8]);
#pragma unroll
        for (int dn = 0; dn < 8; ++dn) {
          const int d = dn * 16 + c16;
          const int cvp = (ks * 4 + hi) ^ (d & 7);
          short8 vf =
              *reinterpret_cast<const short8*>(&Vl[buf][d * 64 + cvp * 8]);
          oacc[dn] =
              __builtin_amdgcn_mfma_f32_16x16x32_bf16(vf, pf, oacc[dn], 0, 0, 0);
        }
      }
      __builtin_amdgcn_s_setprio(0);
    };

    __syncthreads();  // tile 0 staged
    int cur = 0;
    for (int t = 0; t < qt; ++t) {
      stage(t + 1, cur ^ 1);
      tile(t, cur, false);
      __syncthreads();
      cur ^= 1;
    }
    tile(qt, cur, true);

    // epilogue: reduce l across kv-slot groups, write O (pair-packed b32)
    float lt = l_part;
    lt += __shfl_xor(lt, 16);
    lt += __shfl_xor(lt, 32);
    const float inv = 1.f / lt;
    bf16* dst = AO + (size_t)grow * HID_DIM + h * 128;
#pragma unroll
    for (int dn = 0; dn < 8; ++dn) {
#pragma unroll
      for (int w = 0; w < 2; ++w) {
        const unsigned pk = cvtpk_bf16(oacc[dn][2 * w] * inv,
                                       oacc[dn][2 * w + 1] * inv);
        *reinterpret_cast<unsigned*>(&dst[dn * 16 + 4 * hi + 2 * w]) = pk;
      }
    }
  }
}

extern "C" void kernel_launch(void* const* d_in, const int* in_sizes, int n_in,
                              void* d_out, int out_size, void* d_ws,
                              size_t ws_size, hipStream_t stream) {
  (void)in_sizes; (void)n_in; (void)out_size; (void)ws_size;
  const float* hs = (const float*)d_in[0];
  const float* cosb = (const float*)d_in[1];
  const float* sinb = (const float*)d_in[2];
  const float* wq = (const float*)d_in[3];
  const float* wk = (const float*)d_in[4];
  const float* wv = (const float*)d_in[5];
  const float* wo = (const float*)d_in[6];
  const float* qnw = (const float*)d_in[7];
  const float* knw = (const float*)d_in[8];
  float* out = (float*)d_out;
  char* ws = (char*)d_ws;

  bf16* Ah = (bf16*)(ws + 0);              // hidden bf16        16.78 MB
  bf16* Wqkv = (bf16*)(ws + 16777216);     // packed qkv weights 16.78 MB
  bf16* Wo = (bf16*)(ws + 33554432);       // wo bf16             8.39 MB
  bf16* QKVb = (bf16*)(ws + 41943040);     // qkv proj bf16      33.55 MB
  bf16* Qb = (bf16*)(ws + 75497472);       // Q [H][S][D]        16.78 MB
  bf16* Kb = (bf16*)(ws + 92274688);       // K [KV][S][D]        8.39 MB
  bf16* AO = (bf16*)(ws + 109051904);      // attn out [S][H*D]  16.78 MB
  bf16* Vt = (bf16*)(ws + 125829120);      // V^T [KV][128][S]    8.39 MB

  k_cvt4<<<dim3(8192), dim3(256), 0, stream>>>(hs, wq, wk, wv, Ah, Wqkv);
  k_gemm256<bf16><<<dim3(16, 16), dim3(512), 0, stream>>>(Ah, Wqkv, QKVb, 4096,
                                                          4096, 2048);
  k_prep<<<dim3(27136), dim3(256), 0, stream>>>(QKVb, cosb, sinb, qnw, knw, wo,
                                                Qb, Kb, Vt, Wo);
  k_attn<<<dim3(32, 16), dim3(256), 0, stream>>>(Qb, Kb, Vt, AO);
  k_gemm_op<<<dim3(16, 16), dim3(512), 0, stream>>>(AO, Wo, out, 4096, 2048,
                                                    2048);
}